// Round 7
// baseline (65.593 us; speedup 1.0000x reference)
//
#include <hip/hip_runtime.h>
#include <math.h>

#define BATCH 64
#define TLEN  256
#define NCLS  2500
#define BLANK (NCLS - 1)
#define EPSF  1e-7f
#define NF4   (NCLS / 4)                 // 625 float4 per row
#define FULL_IT 9                        // 9*64 = 576; tail = 49
#define TAIL_LANES (NF4 - FULL_IT * 64)  // 49
#define ROWS_PER_WAVE 16                 // 16 waves * 16 rows = 256 = TLEN

typedef float f32x4 __attribute__((ext_vector_type(4)));

// Single fused kernel: one block per batch (64 blocks x 1024 threads).
// Phase 1: each of the 16 waves row-maxes 16 consecutive rows (10KB/row,
// nontemporal float4 loads), results to LDS. Phase 2 (after one barrier):
// threads 0..255 do merge/remove-blank/scan/score from LDS. No atomics,
// no fences, no second dispatch, no workspace.
__global__ __launch_bounds__(1024) void ctc_batch_kernel(
    const float* __restrict__ in, float* __restrict__ dec, float* __restrict__ score) {
  const int b    = blockIdx.x;
  const int wv   = threadIdx.x >> 6;    // 0..15
  const int lane = threadIdx.x & 63;

  __shared__ int   s_best[TLEN];
  __shared__ float s_mlp[TLEN];
  __shared__ int   s_wsum[4];
  __shared__ float s_fsum[4];

  const float* __restrict__ bbase = in + (size_t)b * TLEN * NCLS;

  // ---- phase 1: row argmax, 16 rows per wave ----
  for (int r = 0; r < ROWS_PER_WAVE; ++r) {
    const int row = wv * ROWS_PER_WAVE + r;
    const f32x4* __restrict__ p4 = (const f32x4*)(bbase + (size_t)row * NCLS) + lane;

    f32x4 v[FULL_IT + 1];
    #pragma unroll
    for (int it = 0; it < FULL_IT; ++it) v[it] = __builtin_nontemporal_load(p4 + (it << 6));
    const bool tail = lane < TAIL_LANES;
    if (tail) v[FULL_IT] = __builtin_nontemporal_load(p4 + (FULL_IT << 6));

    float vmax = -1.0f;   // probs >= 0
    int   vidx = 0;
    #pragma unroll
    for (int it = 0; it < FULL_IT; ++it) {     // in-lane idx increasing -> '>' keeps first
      const int base = (it << 8) + (lane << 2);
      if (v[it].x > vmax) { vmax = v[it].x; vidx = base;     }
      if (v[it].y > vmax) { vmax = v[it].y; vidx = base + 1; }
      if (v[it].z > vmax) { vmax = v[it].z; vidx = base + 2; }
      if (v[it].w > vmax) { vmax = v[it].w; vidx = base + 3; }
    }
    if (tail) {
      const int base = (FULL_IT << 8) + (lane << 2);
      if (v[FULL_IT].x > vmax) { vmax = v[FULL_IT].x; vidx = base;     }
      if (v[FULL_IT].y > vmax) { vmax = v[FULL_IT].y; vidx = base + 1; }
      if (v[FULL_IT].z > vmax) { vmax = v[FULL_IT].z; vidx = base + 2; }
      if (v[FULL_IT].w > vmax) { vmax = v[FULL_IT].w; vidx = base + 3; }
    }
    for (int off = 32; off > 0; off >>= 1) {   // larger val wins; tie -> smaller idx
      float ov = __shfl_down(vmax, off);
      int   oi = __shfl_down(vidx, off);
      if (ov > vmax || (ov == vmax && oi < vidx)) { vmax = ov; vidx = oi; }
    }
    if (lane == 0) { s_best[row] = vidx; s_mlp[row] = logf(vmax + EPSF); }
  }

  __syncthreads();   // all rows' best/mlp in LDS

  // ---- phase 2: decode (threads 0..255; all 1024 hit the barriers) ----
  const int t = threadIdx.x;
  int my = 0, keep = 0, x = 0;
  if (t < TLEN) {
    my = s_best[t];
    const int prev = (t == 0) ? -1 : s_best[t - 1];
    keep = (my != BLANK && my != prev) ? 1 : 0;

    x = keep;                              // inclusive wave scan
    #pragma unroll
    for (int off = 1; off < 64; off <<= 1) {
      int y = __shfl_up(x, off);
      if (lane >= off) x += y;
    }
    if (lane == 63) s_wsum[wv] = x;

    float s = s_mlp[t];                    // wave sum of max log-probs
    #pragma unroll
    for (int off = 32; off > 0; off >>= 1) s += __shfl_down(s, off);
    if (lane == 0) s_fsum[wv] = s;
  }
  __syncthreads();

  int pos = 0;
  if (t < TLEN) {
    int offset = 0;
    #pragma unroll
    for (int w = 0; w < 4; ++w) offset += (w < wv) ? s_wsum[w] : 0;
    pos = offset + x - 1;
    dec[b * TLEN + t] = -1.0f;
  }
  __syncthreads();
  if (t < TLEN) {
    if (keep) dec[b * TLEN + pos] = (float)my;
    if (t == 0) score[b] = -(s_fsum[0] + s_fsum[1] + s_fsum[2] + s_fsum[3]);
  }
}

extern "C" void kernel_launch(void* const* d_in, const int* in_sizes, int n_in,
                              void* d_out, int out_size, void* d_ws, size_t ws_size,
                              hipStream_t stream) {
  const float* in = (const float*)d_in[0];
  float* out = (float*)d_out;              // [B*T] decoded (as f32), then [B] scores
  ctc_batch_kernel<<<BATCH, 1024, 0, stream>>>(in, out, out + BATCH * TLEN);
}